// Round 6
// baseline (795.355 us; speedup 1.0000x reference)
//
#include <hip/hip_runtime.h>
#include <stdint.h>

#define T 4096
#define HDIM 1024
#define FDIM 4096
#define NE 8
#define MAXROWS 10240  // 40 tiles of 256; worst padded total = 8192 + 8*255 = 10232

typedef __bf16 bf16x8 __attribute__((ext_vector_type(8)));
typedef float f32x4 __attribute__((ext_vector_type(4)));

__device__ __forceinline__ unsigned short f2bf(float f) {
    unsigned u = __builtin_bit_cast(unsigned, f);
    u += 0x7FFFu + ((u >> 16) & 1u);   // RNE
    return (unsigned short)(u >> 16);
}

// async 16B/lane global->LDS DMA: lds dest = wave-uniform base + lane*16
__device__ __forceinline__ void cp16(const void* g, const void* lds) {
    __builtin_amdgcn_global_load_lds(
        (const __attribute__((address_space(1))) unsigned int*)g,
        (__attribute__((address_space(3))) unsigned int*)(unsigned int)(unsigned long long)lds,
        16, 0, 0);
}

// ---------------- x -> bf16 (with one extra zero row appended by memset) ----
__global__ void conv_x_k(const float* __restrict__ x, unsigned short* __restrict__ xb) {
    size_t i = ((size_t)blockIdx.x * 256 + threadIdx.x) * 8;
    float4 a = *(const float4*)(x + i);
    float4 b = *(const float4*)(x + i + 4);
    uint4 v;
    v.x = (unsigned)f2bf(a.x) | ((unsigned)f2bf(a.y) << 16);
    v.y = (unsigned)f2bf(a.z) | ((unsigned)f2bf(a.w) << 16);
    v.z = (unsigned)f2bf(b.x) | ((unsigned)f2bf(b.y) << 16);
    v.w = (unsigned)f2bf(b.z) | ((unsigned)f2bf(b.w) << 16);
    *(uint4*)(xb + i) = v;
}

// ---------------- merged weight converter (full-F path): all 3 tensors ------
__global__ void conv_all_k(const float* __restrict__ w1, const float* __restrict__ w3,
                           const float* __restrict__ w2,
                           unsigned short* __restrict__ wb1, unsigned short* __restrict__ wb3,
                           unsigned short* __restrict__ wb2) {
    int z = blockIdx.y;
    const float* s = (z == 0) ? w1 : (z == 1) ? w3 : w2;
    unsigned short* d = (z == 0) ? wb1 : (z == 1) ? wb3 : wb2;
    size_t i = ((size_t)blockIdx.x * 256 + threadIdx.x) * 8;
    float4 a = *(const float4*)(s + i);
    float4 b = *(const float4*)(s + i + 4);
    uint4 v;
    v.x = (unsigned)f2bf(a.x) | ((unsigned)f2bf(a.y) << 16);
    v.y = (unsigned)f2bf(a.z) | ((unsigned)f2bf(a.w) << 16);
    v.z = (unsigned)f2bf(b.x) | ((unsigned)f2bf(b.y) << 16);
    v.w = (unsigned)f2bf(b.z) | ((unsigned)f2bf(b.w) << 16);
    *(uint4*)(d + i) = v;
}

// ---------------- chunked weight converters (fallback when ws is small) -----
__global__ void conv_w13_k(const float* __restrict__ src, unsigned short* __restrict__ dst,
                           int f0, int Fc) {
    int e = blockIdx.y;
    size_t rem = ((size_t)blockIdx.x * 256 + threadIdx.x) * 8;
    const float* s = src + ((size_t)e * FDIM + f0) * HDIM + rem;
    unsigned short* d = dst + (size_t)e * Fc * HDIM + rem;
    float4 a = *(const float4*)(s);
    float4 b = *(const float4*)(s + 4);
    uint4 v;
    v.x = (unsigned)f2bf(a.x) | ((unsigned)f2bf(a.y) << 16);
    v.y = (unsigned)f2bf(a.z) | ((unsigned)f2bf(a.w) << 16);
    v.z = (unsigned)f2bf(b.x) | ((unsigned)f2bf(b.y) << 16);
    v.w = (unsigned)f2bf(b.z) | ((unsigned)f2bf(b.w) << 16);
    *(uint4*)(d) = v;
}

__global__ void conv_w2_k(const float* __restrict__ src, unsigned short* __restrict__ dst,
                          int f0, int Fc, int fcShift) {
    int e = blockIdx.y;
    size_t idx = ((size_t)blockIdx.x * 256 + threadIdx.x) * 8;
    int h = (int)(idx >> fcShift);
    int c = (int)(idx & (size_t)(Fc - 1));
    const float* s = src + ((size_t)e * HDIM + h) * FDIM + f0 + c;
    unsigned short* d = dst + (size_t)e * HDIM * Fc + idx;
    float4 a = *(const float4*)(s);
    float4 b = *(const float4*)(s + 4);
    uint4 v;
    v.x = (unsigned)f2bf(a.x) | ((unsigned)f2bf(a.y) << 16);
    v.y = (unsigned)f2bf(a.z) | ((unsigned)f2bf(a.w) << 16);
    v.z = (unsigned)f2bf(b.x) | ((unsigned)f2bf(b.y) << 16);
    v.w = (unsigned)f2bf(b.z) | ((unsigned)f2bf(b.w) << 16);
    *(uint4*)(d) = v;
}

// ---------------- router: logits, top-2, append to expert lists ----------------
__global__ void router_k(const float* __restrict__ x, const float* __restrict__ gw,
                         float* __restrict__ logits_out, int* __restrict__ cnt,
                         int* __restrict__ list, float* __restrict__ wlist) {
    int w = threadIdx.x >> 6, lane = threadIdx.x & 63;
    int t = blockIdx.x * 4 + w;
    float acc[NE];
#pragma unroll
    for (int e = 0; e < NE; ++e) acc[e] = 0.f;
    for (int i = 0; i < HDIM / 64; ++i) {
        int h = i * 64 + lane;
        float xv = x[(size_t)t * HDIM + h];
#pragma unroll
        for (int e = 0; e < NE; ++e) acc[e] += xv * gw[e * HDIM + h];
    }
#pragma unroll
    for (int e = 0; e < NE; ++e)
#pragma unroll
        for (int off = 32; off; off >>= 1) acc[e] += __shfl_xor(acc[e], off);
    if (lane == 0) {
#pragma unroll
        for (int e = 0; e < NE; ++e) logits_out[(size_t)t * NE + e] = acc[e];
        int e1 = 0;
#pragma unroll
        for (int e = 1; e < NE; ++e) if (acc[e] > acc[e1]) e1 = e;
        int e2 = (e1 == 0) ? 1 : 0;
#pragma unroll
        for (int e = 0; e < NE; ++e) { if (e == e1) continue; if (acc[e] > acc[e2]) e2 = e; }
        float wa = 1.f / (1.f + expf(acc[e2] - acc[e1]));
        float wb = 1.f - wa;
        int p1 = atomicAdd(&cnt[e1], 1); list[e1 * T + p1] = t; wlist[e1 * T + p1] = wa;
        int p2 = atomicAdd(&cnt[e2], 1); list[e2 * T + p2] = t; wlist[e2 * T + p2] = wb;
    }
}

// ---------------- padded exclusive prefix over expert counts (256-aligned) ----
__global__ void offsets_k(const int* __restrict__ cnt, int* __restrict__ poff) {
    if (threadIdx.x == 0) {
        int o = 0; poff[0] = 0;
        for (int e = 0; e < NE; ++e) { o += ((cnt[e] + 255) >> 8) << 8; poff[e + 1] = o; }
    }
}

// ---------------- compact lists into padded row space ----------------
__global__ void compact_k(const int* __restrict__ cnt, const int* __restrict__ poff,
                          const int* __restrict__ list, const float* __restrict__ wlist,
                          int* __restrict__ tok_row, float* __restrict__ w_row) {
    int gid = blockIdx.x * 256 + threadIdx.x;  // NE*T threads
    int e = gid >> 12, i = gid & (T - 1);
    int pc = poff[e + 1] - poff[e];
    if (i < pc) {
        int row = poff[e] + i;
        if (i < cnt[e]) { tok_row[row] = list[e * T + i]; w_row[row] = wlist[e * T + i]; }
        else           { tok_row[row] = T;               w_row[row] = 0.f; }
    }
}

// ---------------- GEMM1: inter = silu(x@w1^T) * (x@w3^T), gathered rows ------
// m201-ordered 4-phase K-step (T3+T4+T5): per phase
//   {reads ; stage 2 cp16 ; SB ; s_barrier ; lgkm0 ; SB ; prio1 ; 16 MFMA ;
//    prio0 ; [vmcnt(2) at P1/P4] ; s_barrier}
// Reads are issued BEFORE the begin-barrier so LDS latency completes under
// the barrier-join skew + previous phase's MFMA tail (round-5's
// reads-after-barrier exposed it fully -> 34% MfmaUtil).
// vmcnt ledger (steady state, per wave, stage order A0A1|A2A3|B1B1|B3B3):
//   P4(k-1)-end vmcnt(2): completes A*4+B1*2 of step k   -> P1 reads safe
//   P1(k)-end   vmcnt(2): outstanding={B3(k)*2, A0A1(k+1)*2}; waits oldest 2
//                         = B3(k)                         -> P2 reads safe
//   P2/P3-end: bare.  Tail k=15: P1-end vmcnt(0), no staging.
// LDS tile layout (proven zero-conflict): (row r, chunk cb of 8 bf16) at
//   byte r*128 + ((cb ^ (r&7))*16); linear DMA dest + pre-swizzled global src.
__global__ __launch_bounds__(512, 2) void gemm1_k(
    const unsigned short* __restrict__ xb, const unsigned short* __restrict__ wb1,
    const unsigned short* __restrict__ wb3, const int* __restrict__ tok_row,
    const int* __restrict__ poff, unsigned short* __restrict__ inter, int Fc) {

    __shared__ __align__(16) unsigned short lds[2 * 32768];  // 2 buffers x 64KB
    __shared__ int toks[256];
    __shared__ int e_sh;

    int row0 = blockIdx.y * 256;
    if (row0 >= poff[NE]) return;   // uniform per block
    int tid = threadIdx.x;
    if (tid == 0) { int e = 0; while (row0 >= poff[e + 1]) ++e; e_sh = e; }
    if (tid < 256) toks[tid] = tok_row[row0 + tid];
    __syncthreads();
    int e = e_sh;
    int fr0 = blockIdx.x * 128;
    const unsigned short* w1p = wb1 + ((size_t)e * Fc + fr0) * HDIM;
    const unsigned short* w3p = wb3 + ((size_t)e * Fc + fr0) * HDIM;

    int wv = tid >> 6, lane = tid & 63;
    int quad = lane >> 4, l16 = lane & 15;
    int wm = (wv >> 1) * 64;   // 4 wave-rows x 64 rows
    int wn = (wv & 1) * 64;    // 2 wave-cols x 64 f

    // ---- staging geometry ----
    int sr = lane >> 3;
    int sc = (lane & 7) ^ sr;           // pre-swizzled global chunk
    unsigned a_off[4];
#pragma unroll
    for (int jj = 0; jj < 4; ++jj)
        a_off[jj] = (unsigned)toks[(wv * 4 + jj) * 8 + sr] * HDIM + sc * 8;
    const unsigned short* b1b = w1p + (size_t)(wv * 16 + sr) * HDIM + sc * 8;
    const unsigned short* b3b = w3p + (size_t)(wv * 16 + sr) * HDIM + sc * 8;

    char* ldsc = (char*)lds;
    unsigned dstA  = (unsigned)(wv * 4) * 1024u;
    unsigned dstB1 = 32768u + (unsigned)(wv * 2) * 1024u;
    unsigned dstB3 = 49152u + (unsigned)(wv * 2) * 1024u;

    f32x4 acc1[4][4], acc3[4][4];
#pragma unroll
    for (int a = 0; a < 4; ++a)
#pragma unroll
        for (int b = 0; b < 4; ++b) {
            acc1[a][b] = f32x4{0.f, 0.f, 0.f, 0.f};
            acc3[a][b] = f32x4{0.f, 0.f, 0.f, 0.f};
        }

    // ---- prologue: stage step 0 into buffer 0 (order A,A,A,A,B1,B1,B3,B3) ----
#pragma unroll
    for (int jj = 0; jj < 4; ++jj)
        cp16(xb + a_off[jj], ldsc + dstA + jj * 1024);
    cp16(b1b,                      ldsc + dstB1);
    cp16(b1b + (size_t)8 * HDIM,   ldsc + dstB1 + 1024);
    cp16(b3b,                      ldsc + dstB3);
    cp16(b3b + (size_t)8 * HDIM,   ldsc + dstB3 + 1024);
    // plays the role of P4(-1)-end: publish A,B1 of step 0
    asm volatile("s_waitcnt vmcnt(2)" ::: "memory");
    __builtin_amdgcn_s_barrier();
    __builtin_amdgcn_sched_barrier(0);

    bf16x8 af[4];

    // ---- main loop: steps 0..14 (each stages k+1), step 15 peeled ----
#pragma unroll 1
    for (int k = 0; k < 15; ++k) {
        const unsigned short* sb = lds + (k & 1) * 32768;
        char* db = ldsc + ((k + 1) & 1) * 65536;
        int ko = (k + 1) * 64;

        // ================= P1: acc1 ks0 =================
        {
            bf16x8 b1f[4];
#pragma unroll
            for (int mi = 0; mi < 4; ++mi) {
                int m = wm + mi * 16 + l16;
                af[mi] = *(const bf16x8*)(sb + m * 64 + ((quad ^ (m & 7)) * 8));
            }
#pragma unroll
            for (int ni = 0; ni < 4; ++ni) {
                int n = wn + ni * 16 + l16;
                b1f[ni] = *(const bf16x8*)(sb + 16384 + n * 64 + ((quad ^ (n & 7)) * 8));
            }
            cp16(xb + a_off[0] + ko, db + dstA);
            cp16(xb + a_off[1] + ko, db + dstA + 1024);
            __builtin_amdgcn_sched_barrier(0);
            __builtin_amdgcn_s_barrier();               // begin P1
            asm volatile("s_waitcnt lgkmcnt(0)" ::: "memory");
            __builtin_amdgcn_sched_barrier(0);
            __builtin_amdgcn_s_setprio(1);
#pragma unroll
            for (int ni = 0; ni < 4; ++ni)
#pragma unroll
                for (int mi = 0; mi < 4; ++mi)
                    acc1[mi][ni] = __builtin_amdgcn_mfma_f32_16x16x32_bf16(af[mi], b1f[ni], acc1[mi][ni], 0, 0, 0);
            __builtin_amdgcn_s_setprio(0);
            asm volatile("s_waitcnt vmcnt(2)" ::: "memory");  // publish B3(k)
            __builtin_amdgcn_s_barrier();               // end P1
            __builtin_amdgcn_sched_barrier(0);
        }

        // ================= P2: acc3 ks0 =================
        {
            bf16x8 b3f[4];
#pragma unroll
            for (int ni = 0; ni < 4; ++ni) {
                int n = wn + ni * 16 + l16;
                b3f[ni] = *(const bf16x8*)(sb + 24576 + n * 64 + ((quad ^ (n & 7)) * 8));
            }
            cp16(xb + a_off[2] + ko, db + dstA + 2048);
            cp16(xb + a_off[3] + ko, db + dstA + 3072);
            __builtin_amdgcn_sched_barrier(0);
            __builtin_amdgcn_s_barrier();               // begin P2
            asm volatile("s_waitcnt lgkmcnt(0)" ::: "memory");
            __builtin_amdgcn_sched_barrier(0);
            __builtin_amdgcn_s_setprio(1);
#pragma unroll
            for (int ni = 0; ni < 4; ++ni)
#pragma unroll
                for (int mi = 0; mi < 4; ++mi)
                    acc3[mi][ni] = __builtin_amdgcn_mfma_f32_16x16x32_bf16(af[mi], b3f[ni], acc3[mi][ni], 0, 0, 0);
            __builtin_amdgcn_s_setprio(0);
            __builtin_amdgcn_s_barrier();               // end P2
            __builtin_amdgcn_sched_barrier(0);
        }

        // ================= P3: acc1 ks1 =================
        {
            bf16x8 b1f[4];
            int cb0 = 4 + quad;
#pragma unroll
            for (int mi = 0; mi < 4; ++mi) {
                int m = wm + mi * 16 + l16;
                af[mi] = *(const bf16x8*)(sb + m * 64 + ((cb0 ^ (m & 7)) * 8));
            }
#pragma unroll
            for (int ni = 0; ni < 4; ++ni) {
                int n = wn + ni * 16 + l16;
                b1f[ni] = *(const bf16x8*)(sb + 16384 + n * 64 + ((cb0 ^ (n & 7)) * 8));
            }
            cp16(b1b + ko,                    db + dstB1);
            cp16(b1b + (size_t)8 * HDIM + ko, db + dstB1 + 1024);
            __builtin_amdgcn_sched_barrier(0);
            __builtin_amdgcn_s_barrier();               // begin P3
            asm volatile("s_waitcnt lgkmcnt(0)" ::: "memory");
            __builtin_amdgcn_sched_barrier(0);
            __builtin_amdgcn_s_setprio(1);
#pragma unroll
            for (int ni = 0; ni < 4; ++ni)
#pragma unroll
                for (int mi = 0; mi < 4; ++mi)
                    acc1[mi][ni] = __builtin_amdgcn_mfma_f32_16x16x32_bf16(af[mi], b1f[ni], acc1[mi][ni], 0, 0, 0);
            __builtin_amdgcn_s_setprio(0);
            __builtin_amdgcn_s_barrier();               // end P3
            __builtin_amdgcn_sched_barrier(0);
        }

        // ================= P4: acc3 ks1 =================
        {
            bf16x8 b3f[4];
            int cb0 = 4 + quad;
#pragma unroll
            for (int ni = 0; ni < 4; ++ni) {
                int n = wn + ni * 16 + l16;
                b3f[ni] = *(const bf16x8*)(sb + 24576 + n * 64 + ((cb0 ^ (n & 7)) * 8));
            }
            cp16(b3b + ko,                    db + dstB3);
            cp16(b3b + (size_t)8 * HDIM + ko, db + dstB3 + 1024);
            __builtin_amdgcn_sched_barrier(0);
            __builtin_amdgcn_s_barrier();               // begin P4
            asm volatile("s_waitcnt lgkmcnt(0)" ::: "memory");
            __builtin_amdgcn_sched_barrier(0);
            __builtin_amdgcn_s_setprio(1);
#pragma unroll
            for (int ni = 0; ni < 4; ++ni)
#pragma unroll
                for (int mi = 0; mi < 4; ++mi)
                    acc3[mi][ni] = __builtin_amdgcn_mfma_f32_16x16x32_bf16(af[mi], b3f[ni], acc3[mi][ni], 0, 0, 0);
            __builtin_amdgcn_s_setprio(0);
            asm volatile("s_waitcnt vmcnt(2)" ::: "memory");  // publish A,B1(k+1)
            __builtin_amdgcn_s_barrier();               // end P4
            __builtin_amdgcn_sched_barrier(0);
        }
    }

    // ---- peeled step 15 (no staging) ----
    {
        const unsigned short* sb = lds + 32768;  // 15 & 1

        // P1
        {
            bf16x8 b1f[4];
#pragma unroll
            for (int mi = 0; mi < 4; ++mi) {
                int m = wm + mi * 16 + l16;
                af[mi] = *(const bf16x8*)(sb + m * 64 + ((quad ^ (m & 7)) * 8));
            }
#pragma unroll
            for (int ni = 0; ni < 4; ++ni) {
                int n = wn + ni * 16 + l16;
                b1f[ni] = *(const bf16x8*)(sb + 16384 + n * 64 + ((quad ^ (n & 7)) * 8));
            }
            __builtin_amdgcn_sched_barrier(0);
            __builtin_amdgcn_s_barrier();
            asm volatile("s_waitcnt lgkmcnt(0)" ::: "memory");
            __builtin_amdgcn_sched_barrier(0);
            __builtin_amdgcn_s_setprio(1);
#pragma unroll
            for (int ni = 0; ni < 4; ++ni)
#pragma unroll
                for (int mi = 0; mi < 4; ++mi)
                    acc1[mi][ni] = __builtin_amdgcn_mfma_f32_16x16x32_bf16(af[mi], b1f[ni], acc1[mi][ni], 0, 0, 0);
            __builtin_amdgcn_s_setprio(0);
            asm volatile("s_waitcnt vmcnt(0)" ::: "memory");  // drain B3(15)
            __builtin_amdgcn_s_barrier();
            __builtin_amdgcn_sched_barrier(0);
        }

        // P2
        {
            bf16x8 b3f[4];
#pragma unroll
            for (int ni = 0; ni < 4; ++ni) {
                int n = wn + ni * 16 + l16;
                b3f[ni] = *(const bf16x8*)(sb + 24576 + n * 64 + ((quad ^ (n & 7)) * 8));
            }
            asm volatile("s_waitcnt lgkmcnt(0)" ::: "memory");
            __builtin_amdgcn_sched_barrier(0);
#pragma unroll
            for (int ni = 0; ni < 4; ++ni)
#pragma unroll
                for (int mi = 0; mi < 4; ++mi)
                    acc3[mi][ni] = __builtin_amdgcn_mfma_f32_16x16x32_bf16(af[mi], b3f[ni], acc3[mi][ni], 0, 0, 0);
        }

        // P3
        {
            bf16x8 b1f[4];
            int cb0 = 4 + quad;
#pragma unroll
            for (int mi = 0; mi < 4; ++mi) {
                int m = wm + mi * 16 + l16;
                af[mi] = *(const bf16x8*)(sb + m * 64 + ((cb0 ^ (m & 7)) * 8));
            }
#pragma unroll
            for (int ni = 0; ni < 4; ++ni) {
                int n = wn + ni * 16 + l16;
                b1f[ni] = *(const bf16x8*)(sb + 16384 + n * 64 + ((cb0 ^ (n & 7)) * 8));
            }
            asm volatile("s_waitcnt lgkmcnt(0)" ::: "memory");
            __builtin_amdgcn_sched_barrier(0);
#pragma unroll
            for (int ni = 0; ni < 4; ++ni)
#pragma unroll
                for (int mi = 0; mi < 4; ++mi)
                    acc1[mi][ni] = __builtin_amdgcn_mfma_f32_16x16x32_bf16(af[mi], b1f[ni], acc1[mi][ni], 0, 0, 0);
        }

        // P4
        {
            bf16x8 b3f[4];
            int cb0 = 4 + quad;
#pragma unroll
            for (int ni = 0; ni < 4; ++ni) {
                int n = wn + ni * 16 + l16;
                b3f[ni] = *(const bf16x8*)(sb + 24576 + n * 64 + ((cb0 ^ (n & 7)) * 8));
            }
            asm volatile("s_waitcnt lgkmcnt(0)" ::: "memory");
            __builtin_amdgcn_sched_barrier(0);
#pragma unroll
            for (int ni = 0; ni < 4; ++ni)
#pragma unroll
                for (int mi = 0; mi < 4; ++mi)
                    acc3[mi][ni] = __builtin_amdgcn_mfma_f32_16x16x32_bf16(af[mi], b3f[ni], acc3[mi][ni], 0, 0, 0);
        }
    }

    // ---- epilogue: silu(v1)*v3 -> inter ----
#pragma unroll
    for (int mi = 0; mi < 4; ++mi)
#pragma unroll
        for (int ni = 0; ni < 4; ++ni)
#pragma unroll
            for (int r = 0; r < 4; ++r) {
                int m = wm + mi * 16 + quad * 4 + r;
                int n = wn + ni * 16 + l16;
                float v1 = acc1[mi][ni][r], v3 = acc3[mi][ni][r];
                float hval = (v1 / (1.f + __expf(-v1))) * v3;  // silu(v1)*v3
                inter[(size_t)(row0 + m) * Fc + fr0 + n] = f2bf(hval);
            }
}

// ---------------- GEMM2: out[tok] += w_row * (inter @ w2^T) ----------------
// 128x128, 256 threads, grid x = n-block (fast): co-resident blocks share each
// inter strip; wb2 (64 MB) stays L3-resident across strips.
__global__ __launch_bounds__(256, 3) void gemm2_k(
    const unsigned short* __restrict__ inter, const unsigned short* __restrict__ wb2,
    const int* __restrict__ tok_row, const float* __restrict__ w_row,
    const int* __restrict__ poff, float* __restrict__ out, int Fc) {

    __shared__ __align__(16) unsigned short As[128 * 64];
    __shared__ __align__(16) unsigned short Bs[128 * 64];
    __shared__ int e_sh;

    int row0 = blockIdx.y * 128;
    if (row0 >= poff[NE]) return;
    int tid = threadIdx.x;
    if (tid == 0) { int e = 0; while (row0 >= poff[e + 1]) ++e; e_sh = e; }
    __syncthreads();
    int e = e_sh;
    int n0 = blockIdx.x * 128;

    int wv = tid >> 6, lane = tid & 63;
    int quad = lane >> 4, l16 = lane & 15;
    int wm = (wv >> 1) * 64, wn = (wv & 1) * 64;

    int sr = lane >> 3;
    int sc = (lane & 7) ^ sr;
    const unsigned short* a_b = inter + (size_t)(row0 + wv * 32 + sr) * Fc + sc * 8;
    const unsigned short* b_b = wb2 + ((size_t)e * HDIM + n0 + wv * 32 + sr) * Fc + sc * 8;

    f32x4 acc[4][4];
#pragma unroll
    for (int a = 0; a < 4; ++a)
#pragma unroll
        for (int b = 0; b < 4; ++b) acc[a][b] = f32x4{0.f, 0.f, 0.f, 0.f};

    for (int k0 = 0; k0 < Fc; k0 += 64) {
#pragma unroll
        for (int jj = 0; jj < 4; ++jj) {
            int j = wv * 4 + jj;
            cp16(a_b + (size_t)jj * 8 * Fc + k0, As + j * 512);
            cp16(b_b + (size_t)jj * 8 * Fc + k0, Bs + j * 512);
        }
        __syncthreads();
#pragma unroll
        for (int ks = 0; ks < 2; ++ks) {
            int cb0 = ks * 4 + quad;
            bf16x8 af[4];
#pragma unroll
            for (int mi = 0; mi < 4; ++mi) {
                int m = wm + mi * 16 + l16;
                af[mi] = *(const bf16x8*)(As + m * 64 + ((cb0 ^ (m & 7)) * 8));
            }
#pragma unroll
            for (int ni = 0; ni < 4; ++ni) {
                int n = wn + ni * 16 + l16;
                bf16x8 bf = *(const bf16x8*)(Bs + n * 64 + ((cb0 ^ (n & 7)) * 8));
#pragma unroll
                for (int mi = 0; mi < 4; ++mi)
                    acc[mi][ni] = __builtin_amdgcn_mfma_f32_16x16x32_bf16(af[mi], bf, acc[mi][ni], 0, 0, 0);
            }
        }
        __syncthreads();
    }
#pragma unroll
    for (int mi = 0; mi < 4; ++mi)
#pragma unroll
        for (int r = 0; r < 4; ++r) {
            int m = wm + mi * 16 + quad * 4 + r;
            int grow = row0 + m;
            float wr = w_row[grow];
            if (wr != 0.f) {
                int t = tok_row[grow];
                float* op = out + (size_t)t * HDIM + n0;
#pragma unroll
                for (int ni = 0; ni < 4; ++ni)
                    atomicAdd(op + wn + ni * 16 + l16, wr * acc[mi][ni][r]);
            }
        }
}

extern "C" void kernel_launch(void* const* d_in, const int* in_sizes, int n_in,
                              void* d_out, int out_size, void* d_ws, size_t ws_size,
                              hipStream_t stream) {
    const float* x  = (const float*)d_in[0];
    const float* gw = (const float*)d_in[1];
    const float* w1 = (const float*)d_in[2];
    const float* w2 = (const float*)d_in[3];
    const float* w3 = (const float*)d_in[4];
    float* out = (float*)d_out;
    float* logits = out + (size_t)T * HDIM;

    char* ws = (char*)d_ws;
    size_t off = 0;
    auto alloc = [&](size_t b) {
        off = (off + 255) & ~(size_t)255;
        void* p = ws + off;
        off += b;
        return p;
    };
    int* cnt        = (int*)alloc(NE * 4);
    int* poff       = (int*)alloc((NE + 1) * 4);
    int* list       = (int*)alloc((size_t)NE * T * 4);
    float* wlist    = (float*)alloc((size_t)NE * T * 4);
    int* tok_row    = (int*)alloc(MAXROWS * 4);
    float* w_row    = (float*)alloc(MAXROWS * 4);
    unsigned short* xb = (unsigned short*)alloc((size_t)(T + 1) * HDIM * 2);  // +1 zero row
    size_t fixed_off = off;

    int Fc = 4096, fcShift = 12;
    for (;;) {
        size_t need = fixed_off + 3 * ((size_t)NE * Fc * HDIM * 2) + (size_t)MAXROWS * Fc * 2 + 1024;
        if (need <= ws_size || Fc == 512) break;
        Fc >>= 1; fcShift -= 1;
    }
    unsigned short* wb1 = (unsigned short*)alloc((size_t)NE * Fc * HDIM * 2);
    unsigned short* wb3 = (unsigned short*)alloc((size_t)NE * Fc * HDIM * 2);
    unsigned short* wb2 = (unsigned short*)alloc((size_t)NE * HDIM * Fc * 2);
    unsigned short* inter = (unsigned short*)alloc((size_t)MAXROWS * Fc * 2);

    hipMemsetAsync(cnt, 0, NE * 4, stream);
    hipMemsetAsync(out, 0, (size_t)T * HDIM * 4, stream);
    hipMemsetAsync(xb + (size_t)T * HDIM, 0, HDIM * 2, stream);
    conv_x_k<<<(T * HDIM / 8) / 256, 256, 0, stream>>>(x, xb);
    router_k<<<T / 4, 256, 0, stream>>>(x, gw, logits, cnt, list, wlist);
    offsets_k<<<1, 64, 0, stream>>>(cnt, poff);
    compact_k<<<NE * T / 256, 256, 0, stream>>>(cnt, poff, list, wlist, tok_row, w_row);

    int nMT1 = MAXROWS / 256;  // 40 strips of 256 for gemm1
    int nMT2 = MAXROWS / 128;  // 80 strips of 128 for gemm2
    if (Fc == FDIM) {
        conv_all_k<<<dim3((size_t)NE * FDIM * HDIM / 8 / 256, 3), 256, 0, stream>>>(
            w1, w3, w2, wb1, wb3, wb2);
        gemm1_k<<<dim3(FDIM / 128, nMT1), 512, 0, stream>>>(xb, wb1, wb3, tok_row, poff, inter, FDIM);
        gemm2_k<<<dim3(HDIM / 128, nMT2), 256, 0, stream>>>(inter, wb2, tok_row, w_row, poff, out, FDIM);
    } else {
        for (int f0 = 0; f0 < FDIM; f0 += Fc) {
            conv_w13_k<<<dim3(Fc / 2, NE), 256, 0, stream>>>(w1, wb1, f0, Fc);
            conv_w13_k<<<dim3(Fc / 2, NE), 256, 0, stream>>>(w3, wb3, f0, Fc);
            conv_w2_k<<<dim3(HDIM * Fc / 2048, NE), 256, 0, stream>>>(w2, wb2, f0, Fc, fcShift);
            gemm1_k<<<dim3(Fc / 128, nMT1), 512, 0, stream>>>(xb, wb1, wb3, tok_row, poff, inter, Fc);
            gemm2_k<<<dim3(HDIM / 128, nMT2), 256, 0, stream>>>(inter, wb2, tok_row, w_row, poff, out, Fc);
        }
    }
}

// Round 7
// 781.243 us; speedup vs baseline: 1.0181x; 1.0181x over previous
//
#include <hip/hip_runtime.h>
#include <stdint.h>

#define T 4096
#define HDIM 1024
#define FDIM 4096
#define NE 8
#define MAXROWS 10240  // 40 tiles of 256; worst padded total = 8192 + 8*255 = 10232

typedef __bf16 bf16x8 __attribute__((ext_vector_type(8)));
typedef float f32x4 __attribute__((ext_vector_type(4)));

__device__ __forceinline__ unsigned short f2bf(float f) {
    unsigned u = __builtin_bit_cast(unsigned, f);
    u += 0x7FFFu + ((u >> 16) & 1u);   // RNE
    return (unsigned short)(u >> 16);
}

// async 16B/lane global->LDS DMA: lds dest = wave-uniform base + lane*16
__device__ __forceinline__ void cp16(const void* g, const void* lds) {
    __builtin_amdgcn_global_load_lds(
        (const __attribute__((address_space(1))) unsigned int*)g,
        (__attribute__((address_space(3))) unsigned int*)(unsigned int)(unsigned long long)lds,
        16, 0, 0);
}

// ---------------- x -> bf16 (with one extra zero row appended by memset) ----
__global__ void conv_x_k(const float* __restrict__ x, unsigned short* __restrict__ xb) {
    size_t i = ((size_t)blockIdx.x * 256 + threadIdx.x) * 8;
    float4 a = *(const float4*)(x + i);
    float4 b = *(const float4*)(x + i + 4);
    uint4 v;
    v.x = (unsigned)f2bf(a.x) | ((unsigned)f2bf(a.y) << 16);
    v.y = (unsigned)f2bf(a.z) | ((unsigned)f2bf(a.w) << 16);
    v.z = (unsigned)f2bf(b.x) | ((unsigned)f2bf(b.y) << 16);
    v.w = (unsigned)f2bf(b.z) | ((unsigned)f2bf(b.w) << 16);
    *(uint4*)(xb + i) = v;
}

// ---------------- merged weight converter (full-F path): all 3 tensors ------
__global__ void conv_all_k(const float* __restrict__ w1, const float* __restrict__ w3,
                           const float* __restrict__ w2,
                           unsigned short* __restrict__ wb1, unsigned short* __restrict__ wb3,
                           unsigned short* __restrict__ wb2) {
    int z = blockIdx.y;
    const float* s = (z == 0) ? w1 : (z == 1) ? w3 : w2;
    unsigned short* d = (z == 0) ? wb1 : (z == 1) ? wb3 : wb2;
    size_t i = ((size_t)blockIdx.x * 256 + threadIdx.x) * 8;
    float4 a = *(const float4*)(s + i);
    float4 b = *(const float4*)(s + i + 4);
    uint4 v;
    v.x = (unsigned)f2bf(a.x) | ((unsigned)f2bf(a.y) << 16);
    v.y = (unsigned)f2bf(a.z) | ((unsigned)f2bf(a.w) << 16);
    v.z = (unsigned)f2bf(b.x) | ((unsigned)f2bf(b.y) << 16);
    v.w = (unsigned)f2bf(b.z) | ((unsigned)f2bf(b.w) << 16);
    *(uint4*)(d + i) = v;
}

// ---------------- chunked weight converters (fallback when ws is small) -----
__global__ void conv_w13_k(const float* __restrict__ src, unsigned short* __restrict__ dst,
                           int f0, int Fc) {
    int e = blockIdx.y;
    size_t rem = ((size_t)blockIdx.x * 256 + threadIdx.x) * 8;
    const float* s = src + ((size_t)e * FDIM + f0) * HDIM + rem;
    unsigned short* d = dst + (size_t)e * Fc * HDIM + rem;
    float4 a = *(const float4*)(s);
    float4 b = *(const float4*)(s + 4);
    uint4 v;
    v.x = (unsigned)f2bf(a.x) | ((unsigned)f2bf(a.y) << 16);
    v.y = (unsigned)f2bf(a.z) | ((unsigned)f2bf(a.w) << 16);
    v.z = (unsigned)f2bf(b.x) | ((unsigned)f2bf(b.y) << 16);
    v.w = (unsigned)f2bf(b.z) | ((unsigned)f2bf(b.w) << 16);
    *(uint4*)(d) = v;
}

__global__ void conv_w2_k(const float* __restrict__ src, unsigned short* __restrict__ dst,
                          int f0, int Fc, int fcShift) {
    int e = blockIdx.y;
    size_t idx = ((size_t)blockIdx.x * 256 + threadIdx.x) * 8;
    int h = (int)(idx >> fcShift);
    int c = (int)(idx & (size_t)(Fc - 1));
    const float* s = src + ((size_t)e * HDIM + h) * FDIM + f0 + c;
    unsigned short* d = dst + (size_t)e * HDIM * Fc + idx;
    float4 a = *(const float4*)(s);
    float4 b = *(const float4*)(s + 4);
    uint4 v;
    v.x = (unsigned)f2bf(a.x) | ((unsigned)f2bf(a.y) << 16);
    v.y = (unsigned)f2bf(a.z) | ((unsigned)f2bf(a.w) << 16);
    v.z = (unsigned)f2bf(b.x) | ((unsigned)f2bf(b.y) << 16);
    v.w = (unsigned)f2bf(b.z) | ((unsigned)f2bf(b.w) << 16);
    *(uint4*)(d) = v;
}

// ---------------- router: logits, top-2, block-aggregated list append --------
// 64 blocks x 1024 threads (16 waves), 64 tokens/block (4 per wave).
// Device atomics cut from 8192 RMWs on 8 hot addresses to 512 (one per
// expert per block); within-block positions via fast LDS atomics.
// List order is permutation-invariant (each row carries token + weight).
__global__ __launch_bounds__(1024) void router_k(
    const float* __restrict__ x, const float* __restrict__ gw,
    float* __restrict__ logits_out, int* __restrict__ cnt,
    int* __restrict__ list, float* __restrict__ wlist) {
    __shared__ int   ltok[128];
    __shared__ int   lexp[128];
    __shared__ float lww[128];
    __shared__ int   lpos[128];
    __shared__ int   bcnt[NE];
    __shared__ int   bbase[NE];

    int tid = threadIdx.x, wave = tid >> 6, lane = tid & 63;
    if (tid < NE) bcnt[tid] = 0;

#pragma unroll 1
    for (int j = 0; j < 4; ++j) {
        int t = blockIdx.x * 64 + wave * 4 + j;
        float acc[NE];
#pragma unroll
        for (int e = 0; e < NE; ++e) acc[e] = 0.f;
        for (int i = 0; i < HDIM / 64; ++i) {
            int h = i * 64 + lane;
            float xv = x[(size_t)t * HDIM + h];
#pragma unroll
            for (int e = 0; e < NE; ++e) acc[e] += xv * gw[e * HDIM + h];
        }
#pragma unroll
        for (int e = 0; e < NE; ++e)
#pragma unroll
            for (int off = 32; off; off >>= 1) acc[e] += __shfl_xor(acc[e], off);
        if (lane == 0) {
#pragma unroll
            for (int e = 0; e < NE; ++e) logits_out[(size_t)t * NE + e] = acc[e];
            int e1 = 0;
#pragma unroll
            for (int e = 1; e < NE; ++e) if (acc[e] > acc[e1]) e1 = e;
            int e2 = (e1 == 0) ? 1 : 0;
#pragma unroll
            for (int e = 0; e < NE; ++e) { if (e == e1) continue; if (acc[e] > acc[e2]) e2 = e; }
            float wa = 1.f / (1.f + expf(acc[e2] - acc[e1]));
            float wb = 1.f - wa;
            int s = (wave * 4 + j) * 2;
            ltok[s] = t;     lexp[s] = e1;     lww[s] = wa;
            ltok[s + 1] = t; lexp[s + 1] = e2; lww[s + 1] = wb;
        }
    }
    __syncthreads();
    if (tid < 128) lpos[tid] = atomicAdd(&bcnt[lexp[tid]], 1);   // LDS atomic
    __syncthreads();
    if (tid < NE) bbase[tid] = atomicAdd(&cnt[tid], bcnt[tid]);  // 8 global atomics
    __syncthreads();
    if (tid < 128) {
        int e = lexp[tid];
        int p = bbase[e] + lpos[tid];
        list[e * T + p] = ltok[tid];
        wlist[e * T + p] = lww[tid];
    }
}

// ---------------- padded exclusive prefix over expert counts (256-aligned) ----
__global__ void offsets_k(const int* __restrict__ cnt, int* __restrict__ poff) {
    if (threadIdx.x == 0) {
        int o = 0; poff[0] = 0;
        for (int e = 0; e < NE; ++e) { o += ((cnt[e] + 255) >> 8) << 8; poff[e + 1] = o; }
    }
}

// ---------------- compact lists into padded row space ----------------
__global__ void compact_k(const int* __restrict__ cnt, const int* __restrict__ poff,
                          const int* __restrict__ list, const float* __restrict__ wlist,
                          int* __restrict__ tok_row, float* __restrict__ w_row) {
    int gid = blockIdx.x * 256 + threadIdx.x;  // NE*T threads
    int e = gid >> 12, i = gid & (T - 1);
    int pc = poff[e + 1] - poff[e];
    if (i < pc) {
        int row = poff[e] + i;
        if (i < cnt[e]) { tok_row[row] = list[e * T + i]; w_row[row] = wlist[e * T + i]; }
        else           { tok_row[row] = T;               w_row[row] = 0.f; }
    }
}

// ---------------- GEMM1: inter = silu(x@w1^T) * (x@w3^T), gathered rows ------
// r3 structure (best measured: 176 us): ring-2, issue-next-stage-first, ONE
// __syncthreads per K-step. 512 thr / 8 waves (4M x 2N), BM=256 x BN=128,
// BK=64, 2 LDS buffers of 64KB.
// + XCD swizzle: hw xcd = bx&7 (gridX=32 => lin%8 = bx&7). Remap so all 32
//   f-blocks of one row-strip share one XCD (= its 32 CUs, 1 block/CU):
//   A-strip (512KB gathered xb rows) served from that XCD's L2, not 8x L3.
// LDS tile layout (proven zero-conflict): (row r, chunk cb of 8 bf16) at
//   byte r*128 + ((cb ^ (r&7))*16); linear DMA dest + pre-swizzled global src.
__global__ __launch_bounds__(512, 2) void gemm1_k(
    const unsigned short* __restrict__ xb, const unsigned short* __restrict__ wb1,
    const unsigned short* __restrict__ wb3, const int* __restrict__ tok_row,
    const int* __restrict__ poff, unsigned short* __restrict__ inter, int Fc) {

    __shared__ __align__(16) unsigned short lds[2 * 32768];  // 2 slots x 64KB
    __shared__ int toks[256];
    __shared__ int e_sh;

    // bijective XCD swizzle: (bx>>3, bx&7, by>>3, by&7) -> (Xf, Ys)
    int bx = blockIdx.x, by = blockIdx.y;
    int Xf = (bx >> 3) * 8 + (by & 7);   // f-block   0..31
    int Ys = (by >> 3) * 8 + (bx & 7);   // row strip 0..39 ; same Ys => same xcd

    int row0 = Ys * 256;
    if (row0 >= poff[NE]) return;
    int tid = threadIdx.x;
    if (tid == 0) { int e = 0; while (row0 >= poff[e + 1]) ++e; e_sh = e; }
    if (tid < 256) toks[tid] = tok_row[row0 + tid];
    __syncthreads();
    int e = e_sh;
    int fr0 = Xf * 128;
    const unsigned short* w1p = wb1 + ((size_t)e * Fc + fr0) * HDIM;
    const unsigned short* w3p = wb3 + ((size_t)e * Fc + fr0) * HDIM;

    int wv = tid >> 6, lane = tid & 63;
    int quad = lane >> 4, l16 = lane & 15;
    int wm = (wv >> 1) * 64;   // 4 wave-rows x 64 rows
    int wn = (wv & 1) * 64;    // 2 wave-cols x 64 f

    // ---- staging geometry: thread -> (8-row group j, row sr, swizzled chunk sc)
    int sr = lane >> 3;
    int sc = (lane & 7) ^ sr;           // pre-swizzled global chunk
    unsigned a_off[4];
#pragma unroll
    for (int jj = 0; jj < 4; ++jj)      // A rows: (wv*4+jj)*8 + sr  in 0..255
        a_off[jj] = (unsigned)toks[(wv * 4 + jj) * 8 + sr] * HDIM + sc * 8;
    const unsigned short* b1b = w1p + (size_t)(wv * 16 + sr) * HDIM + sc * 8;
    const unsigned short* b3b = w3p + (size_t)(wv * 16 + sr) * HDIM + sc * 8;

    char* ldsc = (char*)lds;
    unsigned dstA  = (unsigned)(wv * 4) * 1024u;            // + jj*1024
    unsigned dstB1 = 32768u + (unsigned)(wv * 2) * 1024u;   // + jj*1024
    unsigned dstB3 = 49152u + (unsigned)(wv * 2) * 1024u;

    f32x4 acc1[4][4], acc3[4][4];
#pragma unroll
    for (int a = 0; a < 4; ++a)
#pragma unroll
        for (int b = 0; b < 4; ++b) {
            acc1[a][b] = f32x4{0.f, 0.f, 0.f, 0.f};
            acc3[a][b] = f32x4{0.f, 0.f, 0.f, 0.f};
        }

    // ---- prologue: stage K-step 0 into slot 0 ----
#pragma unroll
    for (int jj = 0; jj < 4; ++jj)
        cp16(xb + a_off[jj], ldsc + dstA + jj * 1024);
#pragma unroll
    for (int jj = 0; jj < 2; ++jj) {
        cp16(b1b + (size_t)jj * 8 * HDIM, ldsc + dstB1 + jj * 1024);
        cp16(b3b + (size_t)jj * 8 * HDIM, ldsc + dstB3 + jj * 1024);
    }
    __syncthreads();   // vmcnt(0) drain + barrier: slot 0 resident

    // ---- main loop: 16 K-steps, ring-2, ONE barrier per step ----
#pragma unroll 1
    for (int k = 0; k < 16; ++k) {
        const unsigned short* sb = lds + (k & 1) * 32768;   // current slot (shorts)

        // issue next-step stage FIRST: hides under this step's MFMA cluster
        if (k < 15) {
            char* db = ldsc + ((k + 1) & 1) * 65536;
            int ko = (k + 1) * 64;
#pragma unroll
            for (int jj = 0; jj < 4; ++jj)
                cp16(xb + a_off[jj] + ko, db + dstA + jj * 1024);
#pragma unroll
            for (int jj = 0; jj < 2; ++jj) {
                cp16(b1b + (size_t)jj * 8 * HDIM + ko, db + dstB1 + jj * 1024);
                cp16(b3b + (size_t)jj * 8 * HDIM + ko, db + dstB3 + jj * 1024);
            }
        }

#pragma unroll
        for (int ks = 0; ks < 2; ++ks) {
            int cb0 = ks * 4 + quad;
            bf16x8 af[4], b1f[4], b3f[4];
#pragma unroll
            for (int mi = 0; mi < 4; ++mi) {
                int m = wm + mi * 16 + l16;
                af[mi] = *(const bf16x8*)(sb + m * 64 + ((cb0 ^ (m & 7)) * 8));
            }
#pragma unroll
            for (int ni = 0; ni < 4; ++ni) {
                int n = wn + ni * 16 + l16;
                int sw = (cb0 ^ (n & 7)) * 8;
                b1f[ni] = *(const bf16x8*)(sb + 16384 + n * 64 + sw);
                b3f[ni] = *(const bf16x8*)(sb + 24576 + n * 64 + sw);
            }
            __builtin_amdgcn_s_setprio(1);
#pragma unroll
            for (int ni = 0; ni < 4; ++ni)
#pragma unroll
                for (int mi = 0; mi < 4; ++mi) {
                    acc1[mi][ni] = __builtin_amdgcn_mfma_f32_16x16x32_bf16(af[mi], b1f[ni], acc1[mi][ni], 0, 0, 0);
                    acc3[mi][ni] = __builtin_amdgcn_mfma_f32_16x16x32_bf16(af[mi], b3f[ni], acc3[mi][ni], 0, 0, 0);
                }
            __builtin_amdgcn_s_setprio(0);
        }
        // vmcnt(0)+lgkmcnt(0)+barrier: publishes slot k+1, protects slot k
        __syncthreads();
    }

    // ---- epilogue: silu(v1)*v3 -> inter ----
#pragma unroll
    for (int mi = 0; mi < 4; ++mi)
#pragma unroll
        for (int ni = 0; ni < 4; ++ni)
#pragma unroll
            for (int r = 0; r < 4; ++r) {
                int m = wm + mi * 16 + quad * 4 + r;
                int n = wn + ni * 16 + l16;
                float v1 = acc1[mi][ni][r], v3 = acc3[mi][ni][r];
                float hval = (v1 / (1.f + __expf(-v1))) * v3;  // silu(v1)*v3
                inter[(size_t)(row0 + m) * Fc + fr0 + n] = f2bf(hval);
            }
}

// ---------------- GEMM2: out[tok] += w_row * (inter @ w2^T) ----------------
// Ring-2 issue-early pipeline (r3-proven pattern), 64 K-steps amortize it.
// 128x128, 256 thr / 4 waves, 2 LDS buffers of 32KB -> 2 blocks/CU.
// + XCD swizzle: gridX=8 => hw xcd = bx. Remap so the 8 n-blocks of one
//   row-strip are co-XCD: inter strip (1MB) served from that XCD's L2.
__global__ __launch_bounds__(256, 2) void gemm2_k(
    const unsigned short* __restrict__ inter, const unsigned short* __restrict__ wb2,
    const int* __restrict__ tok_row, const float* __restrict__ w_row,
    const int* __restrict__ poff, float* __restrict__ out, int Fc) {

    __shared__ __align__(16) unsigned short lds[2 * 16384];  // 2 slots x 32KB
    __shared__ int e_sh;

    // bijective swizzle: X = by&7 (n-block 0..7), Y = (by>>3)*8 + bx (strip 0..79)
    int bx = blockIdx.x, by = blockIdx.y;
    int Xn = by & 7;
    int Ys = (by >> 3) * 8 + bx;

    int row0 = Ys * 128;
    if (row0 >= poff[NE]) return;
    int tid = threadIdx.x;
    if (tid == 0) { int e = 0; while (row0 >= poff[e + 1]) ++e; e_sh = e; }
    __syncthreads();
    int e = e_sh;
    int n0 = Xn * 128;

    int wv = tid >> 6, lane = tid & 63;
    int quad = lane >> 4, l16 = lane & 15;
    int wm = (wv >> 1) * 64, wn = (wv & 1) * 64;

    int sr = lane >> 3;
    int sc = (lane & 7) ^ sr;
    const unsigned short* a_b = inter + (size_t)(row0 + wv * 32 + sr) * Fc + sc * 8;
    const unsigned short* b_b = wb2 + ((size_t)e * HDIM + n0 + wv * 32 + sr) * Fc + sc * 8;

    char* ldsc = (char*)lds;

    f32x4 acc[4][4];
#pragma unroll
    for (int a = 0; a < 4; ++a)
#pragma unroll
        for (int b = 0; b < 4; ++b) acc[a][b] = f32x4{0.f, 0.f, 0.f, 0.f};

    // ---- prologue: stage K-step 0 into slot 0 ----
#pragma unroll
    for (int jj = 0; jj < 4; ++jj) {
        int j = wv * 4 + jj;
        cp16(a_b + (size_t)jj * 8 * Fc, ldsc + j * 1024);
        cp16(b_b + (size_t)jj * 8 * Fc, ldsc + 16384 + j * 1024);
    }
    __syncthreads();

    // ---- main loop: 64 K-steps, ring-2, ONE barrier per step ----
#pragma unroll 1
    for (int k = 0; k < 64; ++k) {
        const unsigned short* sb = lds + (k & 1) * 16384;   // slot base (shorts)

        if (k < 63) {
            char* db = ldsc + ((k + 1) & 1) * 32768;
            int ko = (k + 1) * 64;
#pragma unroll
            for (int jj = 0; jj < 4; ++jj) {
                int j = wv * 4 + jj;
                cp16(a_b + (size_t)jj * 8 * Fc + ko, db + j * 1024);
                cp16(b_b + (size_t)jj * 8 * Fc + ko, db + 16384 + j * 1024);
            }
        }

#pragma unroll
        for (int ks = 0; ks < 2; ++ks) {
            int cb0 = ks * 4 + quad;
            bf16x8 af[4];
#pragma unroll
            for (int mi = 0; mi < 4; ++mi) {
                int m = wm + mi * 16 + l16;
                af[mi] = *(const bf16x8*)(sb + m * 64 + ((cb0 ^ (m & 7)) * 8));
            }
#pragma unroll
            for (int ni = 0; ni < 4; ++ni) {
                int n = wn + ni * 16 + l16;
                bf16x8 bf = *(const bf16x8*)(sb + 8192 + n * 64 + ((cb0 ^ (n & 7)) * 8));
#pragma unroll
                for (int mi = 0; mi < 4; ++mi)
                    acc[mi][ni] = __builtin_amdgcn_mfma_f32_16x16x32_bf16(af[mi], bf, acc[mi][ni], 0, 0, 0);
            }
        }
        __syncthreads();
    }

#pragma unroll
    for (int mi = 0; mi < 4; ++mi)
#pragma unroll
        for (int r = 0; r < 4; ++r) {
            int m = wm + mi * 16 + quad * 4 + r;
            int grow = row0 + m;
            float wr = w_row[grow];
            if (wr != 0.f) {
                int t = tok_row[grow];
                float* op = out + (size_t)t * HDIM + n0;
#pragma unroll
                for (int ni = 0; ni < 4; ++ni)
                    atomicAdd(op + wn + ni * 16 + l16, wr * acc[mi][ni][r]);
            }
        }
}

extern "C" void kernel_launch(void* const* d_in, const int* in_sizes, int n_in,
                              void* d_out, int out_size, void* d_ws, size_t ws_size,
                              hipStream_t stream) {
    const float* x  = (const float*)d_in[0];
    const float* gw = (const float*)d_in[1];
    const float* w1 = (const float*)d_in[2];
    const float* w2 = (const float*)d_in[3];
    const float* w3 = (const float*)d_in[4];
    float* out = (float*)d_out;
    float* logits = out + (size_t)T * HDIM;

    char* ws = (char*)d_ws;
    size_t off = 0;
    auto alloc = [&](size_t b) {
        off = (off + 255) & ~(size_t)255;
        void* p = ws + off;
        off += b;
        return p;
    };
    int* cnt        = (int*)alloc(NE * 4);
    int* poff       = (int*)alloc((NE + 1) * 4);
    int* list       = (int*)alloc((size_t)NE * T * 4);
    float* wlist    = (float*)alloc((size_t)NE * T * 4);
    int* tok_row    = (int*)alloc(MAXROWS * 4);
    float* w_row    = (float*)alloc(MAXROWS * 4);
    unsigned short* xb = (unsigned short*)alloc((size_t)(T + 1) * HDIM * 2);  // +1 zero row
    size_t fixed_off = off;

    int Fc = 4096, fcShift = 12;
    for (;;) {
        size_t need = fixed_off + 3 * ((size_t)NE * Fc * HDIM * 2) + (size_t)MAXROWS * Fc * 2 + 1024;
        if (need <= ws_size || Fc == 512) break;
        Fc >>= 1; fcShift -= 1;
    }
    unsigned short* wb1 = (unsigned short*)alloc((size_t)NE * Fc * HDIM * 2);
    unsigned short* wb3 = (unsigned short*)alloc((size_t)NE * Fc * HDIM * 2);
    unsigned short* wb2 = (unsigned short*)alloc((size_t)NE * HDIM * Fc * 2);
    unsigned short* inter = (unsigned short*)alloc((size_t)MAXROWS * Fc * 2);

    hipMemsetAsync(cnt, 0, NE * 4, stream);
    hipMemsetAsync(out, 0, (size_t)T * HDIM * 4, stream);
    hipMemsetAsync(xb + (size_t)T * HDIM, 0, HDIM * 2, stream);
    conv_x_k<<<(T * HDIM / 8) / 256, 256, 0, stream>>>(x, xb);
    router_k<<<T / 64, 1024, 0, stream>>>(x, gw, logits, cnt, list, wlist);
    offsets_k<<<1, 64, 0, stream>>>(cnt, poff);
    compact_k<<<NE * T / 256, 256, 0, stream>>>(cnt, poff, list, wlist, tok_row, w_row);

    int nMT1 = MAXROWS / 256;  // 40 strips of 256 for gemm1
    int nMT2 = MAXROWS / 128;  // 80 strips of 128 for gemm2
    if (Fc == FDIM) {
        conv_all_k<<<dim3((size_t)NE * FDIM * HDIM / 8 / 256, 3), 256, 0, stream>>>(
            w1, w3, w2, wb1, wb3, wb2);
        gemm1_k<<<dim3(FDIM / 128, nMT1), 512, 0, stream>>>(xb, wb1, wb3, tok_row, poff, inter, FDIM);
        gemm2_k<<<dim3(HDIM / 128, nMT2), 256, 0, stream>>>(inter, wb2, tok_row, w_row, poff, out, FDIM);
    } else {
        for (int f0 = 0; f0 < FDIM; f0 += Fc) {
            conv_w13_k<<<dim3(Fc / 2, NE), 256, 0, stream>>>(w1, wb1, f0, Fc);
            conv_w13_k<<<dim3(Fc / 2, NE), 256, 0, stream>>>(w3, wb3, f0, Fc);
            conv_w2_k<<<dim3(HDIM * Fc / 2048, NE), 256, 0, stream>>>(w2, wb2, f0, Fc, fcShift);
            gemm1_k<<<dim3(Fc / 128, nMT1), 512, 0, stream>>>(xb, wb1, wb3, tok_row, poff, inter, Fc);
            gemm2_k<<<dim3(HDIM / 128, nMT2), 256, 0, stream>>>(inter, wb2, tok_row, w_row, poff, out, Fc);
        }
    }
}

// Round 8
// 755.480 us; speedup vs baseline: 1.0528x; 1.0341x over previous
//
#include <hip/hip_runtime.h>
#include <stdint.h>

#define T 4096
#define HDIM 1024
#define FDIM 4096
#define NE 8
#define MAXROWS 10240  // 40 tiles of 256; worst padded total = 8192 + 8*255 = 10232

typedef __bf16 bf16x8 __attribute__((ext_vector_type(8)));
typedef float f32x4 __attribute__((ext_vector_type(4)));

__device__ __forceinline__ unsigned short f2bf(float f) {
    unsigned u = __builtin_bit_cast(unsigned, f);
    u += 0x7FFFu + ((u >> 16) & 1u);   // RNE
    return (unsigned short)(u >> 16);
}

// async 16B/lane global->LDS DMA: lds dest = wave-uniform base + lane*16
__device__ __forceinline__ void cp16(const void* g, const void* lds) {
    __builtin_amdgcn_global_load_lds(
        (const __attribute__((address_space(1))) unsigned int*)g,
        (__attribute__((address_space(3))) unsigned int*)(unsigned int)(unsigned long long)lds,
        16, 0, 0);
}

// ---------------- x -> bf16 (with one extra zero row appended by memset) ----
__global__ void conv_x_k(const float* __restrict__ x, unsigned short* __restrict__ xb) {
    size_t i = ((size_t)blockIdx.x * 256 + threadIdx.x) * 8;
    float4 a = *(const float4*)(x + i);
    float4 b = *(const float4*)(x + i + 4);
    uint4 v;
    v.x = (unsigned)f2bf(a.x) | ((unsigned)f2bf(a.y) << 16);
    v.y = (unsigned)f2bf(a.z) | ((unsigned)f2bf(a.w) << 16);
    v.z = (unsigned)f2bf(b.x) | ((unsigned)f2bf(b.y) << 16);
    v.w = (unsigned)f2bf(b.z) | ((unsigned)f2bf(b.w) << 16);
    *(uint4*)(xb + i) = v;
}

// ---------------- merged weight converter (full-F path): all 3 tensors ------
__global__ void conv_all_k(const float* __restrict__ w1, const float* __restrict__ w3,
                           const float* __restrict__ w2,
                           unsigned short* __restrict__ wb1, unsigned short* __restrict__ wb3,
                           unsigned short* __restrict__ wb2) {
    int z = blockIdx.y;
    const float* s = (z == 0) ? w1 : (z == 1) ? w3 : w2;
    unsigned short* d = (z == 0) ? wb1 : (z == 1) ? wb3 : wb2;
    size_t i = ((size_t)blockIdx.x * 256 + threadIdx.x) * 8;
    float4 a = *(const float4*)(s + i);
    float4 b = *(const float4*)(s + i + 4);
    uint4 v;
    v.x = (unsigned)f2bf(a.x) | ((unsigned)f2bf(a.y) << 16);
    v.y = (unsigned)f2bf(a.z) | ((unsigned)f2bf(a.w) << 16);
    v.z = (unsigned)f2bf(b.x) | ((unsigned)f2bf(b.y) << 16);
    v.w = (unsigned)f2bf(b.z) | ((unsigned)f2bf(b.w) << 16);
    *(uint4*)(d + i) = v;
}

// ---------------- chunked weight converters (fallback when ws is small) -----
__global__ void conv_w13_k(const float* __restrict__ src, unsigned short* __restrict__ dst,
                           int f0, int Fc) {
    int e = blockIdx.y;
    size_t rem = ((size_t)blockIdx.x * 256 + threadIdx.x) * 8;
    const float* s = src + ((size_t)e * FDIM + f0) * HDIM + rem;
    unsigned short* d = dst + (size_t)e * Fc * HDIM + rem;
    float4 a = *(const float4*)(s);
    float4 b = *(const float4*)(s + 4);
    uint4 v;
    v.x = (unsigned)f2bf(a.x) | ((unsigned)f2bf(a.y) << 16);
    v.y = (unsigned)f2bf(a.z) | ((unsigned)f2bf(a.w) << 16);
    v.z = (unsigned)f2bf(b.x) | ((unsigned)f2bf(b.y) << 16);
    v.w = (unsigned)f2bf(b.z) | ((unsigned)f2bf(b.w) << 16);
    *(uint4*)(d) = v;
}

__global__ void conv_w2_k(const float* __restrict__ src, unsigned short* __restrict__ dst,
                          int f0, int Fc, int fcShift) {
    int e = blockIdx.y;
    size_t idx = ((size_t)blockIdx.x * 256 + threadIdx.x) * 8;
    int h = (int)(idx >> fcShift);
    int c = (int)(idx & (size_t)(Fc - 1));
    const float* s = src + ((size_t)e * HDIM + h) * FDIM + f0 + c;
    unsigned short* d = dst + (size_t)e * HDIM * Fc + idx;
    float4 a = *(const float4*)(s);
    float4 b = *(const float4*)(s + 4);
    uint4 v;
    v.x = (unsigned)f2bf(a.x) | ((unsigned)f2bf(a.y) << 16);
    v.y = (unsigned)f2bf(a.z) | ((unsigned)f2bf(a.w) << 16);
    v.z = (unsigned)f2bf(b.x) | ((unsigned)f2bf(b.y) << 16);
    v.w = (unsigned)f2bf(b.z) | ((unsigned)f2bf(b.w) << 16);
    *(uint4*)(d) = v;
}

// ---------------- router: logits, top-2, block-aggregated list append --------
// 64 blocks x 1024 threads (16 waves), 64 tokens/block (4 per wave).
// Device atomics cut from 8192 RMWs on 8 hot addresses to 512 (one per
// expert per block); within-block positions via fast LDS atomics.
// List order is permutation-invariant (each row carries token + weight).
__global__ __launch_bounds__(1024) void router_k(
    const float* __restrict__ x, const float* __restrict__ gw,
    float* __restrict__ logits_out, int* __restrict__ cnt,
    int* __restrict__ list, float* __restrict__ wlist) {
    __shared__ int   ltok[128];
    __shared__ int   lexp[128];
    __shared__ float lww[128];
    __shared__ int   lpos[128];
    __shared__ int   bcnt[NE];
    __shared__ int   bbase[NE];

    int tid = threadIdx.x, wave = tid >> 6, lane = tid & 63;
    if (tid < NE) bcnt[tid] = 0;

#pragma unroll 1
    for (int j = 0; j < 4; ++j) {
        int t = blockIdx.x * 64 + wave * 4 + j;
        float acc[NE];
#pragma unroll
        for (int e = 0; e < NE; ++e) acc[e] = 0.f;
        for (int i = 0; i < HDIM / 64; ++i) {
            int h = i * 64 + lane;
            float xv = x[(size_t)t * HDIM + h];
#pragma unroll
            for (int e = 0; e < NE; ++e) acc[e] += xv * gw[e * HDIM + h];
        }
#pragma unroll
        for (int e = 0; e < NE; ++e)
#pragma unroll
            for (int off = 32; off; off >>= 1) acc[e] += __shfl_xor(acc[e], off);
        if (lane == 0) {
#pragma unroll
            for (int e = 0; e < NE; ++e) logits_out[(size_t)t * NE + e] = acc[e];
            int e1 = 0;
#pragma unroll
            for (int e = 1; e < NE; ++e) if (acc[e] > acc[e1]) e1 = e;
            int e2 = (e1 == 0) ? 1 : 0;
#pragma unroll
            for (int e = 0; e < NE; ++e) { if (e == e1) continue; if (acc[e] > acc[e2]) e2 = e; }
            float wa = 1.f / (1.f + expf(acc[e2] - acc[e1]));
            float wb = 1.f - wa;
            int s = (wave * 4 + j) * 2;
            ltok[s] = t;     lexp[s] = e1;     lww[s] = wa;
            ltok[s + 1] = t; lexp[s + 1] = e2; lww[s + 1] = wb;
        }
    }
    __syncthreads();
    if (tid < 128) lpos[tid] = atomicAdd(&bcnt[lexp[tid]], 1);   // LDS atomic
    __syncthreads();
    if (tid < NE) bbase[tid] = atomicAdd(&cnt[tid], bcnt[tid]);  // 8 global atomics
    __syncthreads();
    if (tid < 128) {
        int e = lexp[tid];
        int p = bbase[e] + lpos[tid];
        list[e * T + p] = ltok[tid];
        wlist[e * T + p] = lww[tid];
    }
}

// ---------------- padded exclusive prefix over expert counts (256-aligned) ----
__global__ void offsets_k(const int* __restrict__ cnt, int* __restrict__ poff) {
    if (threadIdx.x == 0) {
        int o = 0; poff[0] = 0;
        for (int e = 0; e < NE; ++e) { o += ((cnt[e] + 255) >> 8) << 8; poff[e + 1] = o; }
    }
}

// ---------------- compact lists into padded row space ----------------
__global__ void compact_k(const int* __restrict__ cnt, const int* __restrict__ poff,
                          const int* __restrict__ list, const float* __restrict__ wlist,
                          int* __restrict__ tok_row, float* __restrict__ w_row) {
    int gid = blockIdx.x * 256 + threadIdx.x;  // NE*T threads
    int e = gid >> 12, i = gid & (T - 1);
    int pc = poff[e + 1] - poff[e];
    if (i < pc) {
        int row = poff[e] + i;
        if (i < cnt[e]) { tok_row[row] = list[e * T + i]; w_row[row] = wlist[e * T + i]; }
        else           { tok_row[row] = T;               w_row[row] = 0.f; }
    }
}

// ---------------- GEMM1: inter = silu(x@w1^T) * (x@w3^T), gathered rows ------
// r3 structure (best measured: 176 us): ring-2, issue-next-stage-first, ONE
// __syncthreads per K-step. 512 thr / 8 waves (4M x 2N), BM=256 x BN=128,
// BK=64, 2 LDS buffers of 64KB.
// NOTE on block mapping (r7 lesson, FETCH 160->295MB regression): keep the
// NATURAL bx/by mapping. With gridX=32, xcd = (bx+32*by)%8 = bx%8, so all
// co-resident blocks sharing a weight panel (same bx, different strips)
// already sit on the SAME XCD -> each 512KB panel hits L2 once, shared by
// 8 strips. Traffic is weight-dominated (128MB wb1+wb3 vs 16MB A), so any
// swizzle that trades weight locality for A locality doubles HBM fetch.
// LDS tile layout (proven zero-conflict): (row r, chunk cb of 8 bf16) at
//   byte r*128 + ((cb ^ (r&7))*16); linear DMA dest + pre-swizzled global src.
__global__ __launch_bounds__(512, 2) void gemm1_k(
    const unsigned short* __restrict__ xb, const unsigned short* __restrict__ wb1,
    const unsigned short* __restrict__ wb3, const int* __restrict__ tok_row,
    const int* __restrict__ poff, unsigned short* __restrict__ inter, int Fc) {

    __shared__ __align__(16) unsigned short lds[2 * 32768];  // 2 slots x 64KB
    __shared__ int toks[256];
    __shared__ int e_sh;

    int row0 = blockIdx.y * 256;
    if (row0 >= poff[NE]) return;
    int tid = threadIdx.x;
    if (tid == 0) { int e = 0; while (row0 >= poff[e + 1]) ++e; e_sh = e; }
    if (tid < 256) toks[tid] = tok_row[row0 + tid];
    __syncthreads();
    int e = e_sh;
    int fr0 = blockIdx.x * 128;
    const unsigned short* w1p = wb1 + ((size_t)e * Fc + fr0) * HDIM;
    const unsigned short* w3p = wb3 + ((size_t)e * Fc + fr0) * HDIM;

    int wv = tid >> 6, lane = tid & 63;
    int quad = lane >> 4, l16 = lane & 15;
    int wm = (wv >> 1) * 64;   // 4 wave-rows x 64 rows
    int wn = (wv & 1) * 64;    // 2 wave-cols x 64 f

    // ---- staging geometry: thread -> (8-row group j, row sr, swizzled chunk sc)
    int sr = lane >> 3;
    int sc = (lane & 7) ^ sr;           // pre-swizzled global chunk
    unsigned a_off[4];
#pragma unroll
    for (int jj = 0; jj < 4; ++jj)      // A rows: (wv*4+jj)*8 + sr  in 0..255
        a_off[jj] = (unsigned)toks[(wv * 4 + jj) * 8 + sr] * HDIM + sc * 8;
    const unsigned short* b1b = w1p + (size_t)(wv * 16 + sr) * HDIM + sc * 8;
    const unsigned short* b3b = w3p + (size_t)(wv * 16 + sr) * HDIM + sc * 8;

    char* ldsc = (char*)lds;
    unsigned dstA  = (unsigned)(wv * 4) * 1024u;            // + jj*1024
    unsigned dstB1 = 32768u + (unsigned)(wv * 2) * 1024u;   // + jj*1024
    unsigned dstB3 = 49152u + (unsigned)(wv * 2) * 1024u;

    f32x4 acc1[4][4], acc3[4][4];
#pragma unroll
    for (int a = 0; a < 4; ++a)
#pragma unroll
        for (int b = 0; b < 4; ++b) {
            acc1[a][b] = f32x4{0.f, 0.f, 0.f, 0.f};
            acc3[a][b] = f32x4{0.f, 0.f, 0.f, 0.f};
        }

    // ---- prologue: stage K-step 0 into slot 0 ----
#pragma unroll
    for (int jj = 0; jj < 4; ++jj)
        cp16(xb + a_off[jj], ldsc + dstA + jj * 1024);
#pragma unroll
    for (int jj = 0; jj < 2; ++jj) {
        cp16(b1b + (size_t)jj * 8 * HDIM, ldsc + dstB1 + jj * 1024);
        cp16(b3b + (size_t)jj * 8 * HDIM, ldsc + dstB3 + jj * 1024);
    }
    __syncthreads();   // vmcnt(0) drain + barrier: slot 0 resident

    // ---- main loop: 16 K-steps, ring-2, ONE barrier per step ----
#pragma unroll 1
    for (int k = 0; k < 16; ++k) {
        const unsigned short* sb = lds + (k & 1) * 32768;   // current slot (shorts)

        // issue next-step stage FIRST: hides under this step's MFMA cluster
        if (k < 15) {
            char* db = ldsc + ((k + 1) & 1) * 65536;
            int ko = (k + 1) * 64;
#pragma unroll
            for (int jj = 0; jj < 4; ++jj)
                cp16(xb + a_off[jj] + ko, db + dstA + jj * 1024);
#pragma unroll
            for (int jj = 0; jj < 2; ++jj) {
                cp16(b1b + (size_t)jj * 8 * HDIM + ko, db + dstB1 + jj * 1024);
                cp16(b3b + (size_t)jj * 8 * HDIM + ko, db + dstB3 + jj * 1024);
            }
        }

#pragma unroll
        for (int ks = 0; ks < 2; ++ks) {
            int cb0 = ks * 4 + quad;
            bf16x8 af[4], b1f[4], b3f[4];
#pragma unroll
            for (int mi = 0; mi < 4; ++mi) {
                int m = wm + mi * 16 + l16;
                af[mi] = *(const bf16x8*)(sb + m * 64 + ((cb0 ^ (m & 7)) * 8));
            }
#pragma unroll
            for (int ni = 0; ni < 4; ++ni) {
                int n = wn + ni * 16 + l16;
                int sw = (cb0 ^ (n & 7)) * 8;
                b1f[ni] = *(const bf16x8*)(sb + 16384 + n * 64 + sw);
                b3f[ni] = *(const bf16x8*)(sb + 24576 + n * 64 + sw);
            }
            __builtin_amdgcn_s_setprio(1);
#pragma unroll
            for (int ni = 0; ni < 4; ++ni)
#pragma unroll
                for (int mi = 0; mi < 4; ++mi) {
                    acc1[mi][ni] = __builtin_amdgcn_mfma_f32_16x16x32_bf16(af[mi], b1f[ni], acc1[mi][ni], 0, 0, 0);
                    acc3[mi][ni] = __builtin_amdgcn_mfma_f32_16x16x32_bf16(af[mi], b3f[ni], acc3[mi][ni], 0, 0, 0);
                }
            __builtin_amdgcn_s_setprio(0);
        }
        // vmcnt(0)+lgkmcnt(0)+barrier: publishes slot k+1, protects slot k
        __syncthreads();
    }

    // ---- epilogue: silu(v1)*v3 -> inter ----
#pragma unroll
    for (int mi = 0; mi < 4; ++mi)
#pragma unroll
        for (int ni = 0; ni < 4; ++ni)
#pragma unroll
            for (int r = 0; r < 4; ++r) {
                int m = wm + mi * 16 + quad * 4 + r;
                int n = wn + ni * 16 + l16;
                float v1 = acc1[mi][ni][r], v3 = acc3[mi][ni][r];
                float hval = (v1 / (1.f + __expf(-v1))) * v3;  // silu(v1)*v3
                inter[(size_t)(row0 + m) * Fc + fr0 + n] = f2bf(hval);
            }
}

// ---------------- GEMM2: out[tok] += w_row * (inter @ w2^T) ----------------
// Ring-2 issue-early pipeline (r3-proven pattern), 64 K-steps amortize it.
// 128x128, 256 thr / 4 waves, 2 LDS buffers of 32KB -> 2 blocks/CU.
// + XCD swizzle: gridX=8 => hw xcd = bx. Remap so the 8 n-blocks of one
//   row-strip are co-XCD: inter strip (1MB) served from that XCD's L2.
//   (Kept from r7: gemm2 traffic is inter-strip + wb2, and wb2 panels are
//   shared across ALL strips so they L3-hit regardless; measured as part of
//   r7's ~20us rest-of-pipeline win.)
__global__ __launch_bounds__(256, 2) void gemm2_k(
    const unsigned short* __restrict__ inter, const unsigned short* __restrict__ wb2,
    const int* __restrict__ tok_row, const float* __restrict__ w_row,
    const int* __restrict__ poff, float* __restrict__ out, int Fc) {

    __shared__ __align__(16) unsigned short lds[2 * 16384];  // 2 slots x 32KB
    __shared__ int e_sh;

    // bijective swizzle: X = by&7 (n-block 0..7), Y = (by>>3)*8 + bx (strip 0..79)
    int bx = blockIdx.x, by = blockIdx.y;
    int Xn = by & 7;
    int Ys = (by >> 3) * 8 + bx;

    int row0 = Ys * 128;
    if (row0 >= poff[NE]) return;
    int tid = threadIdx.x;
    if (tid == 0) { int e = 0; while (row0 >= poff[e + 1]) ++e; e_sh = e; }
    __syncthreads();
    int e = e_sh;
    int n0 = Xn * 128;

    int wv = tid >> 6, lane = tid & 63;
    int quad = lane >> 4, l16 = lane & 15;
    int wm = (wv >> 1) * 64, wn = (wv & 1) * 64;

    int sr = lane >> 3;
    int sc = (lane & 7) ^ sr;
    const unsigned short* a_b = inter + (size_t)(row0 + wv * 32 + sr) * Fc + sc * 8;
    const unsigned short* b_b = wb2 + ((size_t)e * HDIM + n0 + wv * 32 + sr) * Fc + sc * 8;

    char* ldsc = (char*)lds;

    f32x4 acc[4][4];
#pragma unroll
    for (int a = 0; a < 4; ++a)
#pragma unroll
        for (int b = 0; b < 4; ++b) acc[a][b] = f32x4{0.f, 0.f, 0.f, 0.f};

    // ---- prologue: stage K-step 0 into slot 0 ----
#pragma unroll
    for (int jj = 0; jj < 4; ++jj) {
        int j = wv * 4 + jj;
        cp16(a_b + (size_t)jj * 8 * Fc, ldsc + j * 1024);
        cp16(b_b + (size_t)jj * 8 * Fc, ldsc + 16384 + j * 1024);
    }
    __syncthreads();

    // ---- main loop: 64 K-steps, ring-2, ONE barrier per step ----
#pragma unroll 1
    for (int k = 0; k < 64; ++k) {
        const unsigned short* sb = lds + (k & 1) * 16384;   // slot base (shorts)

        if (k < 63) {
            char* db = ldsc + ((k + 1) & 1) * 32768;
            int ko = (k + 1) * 64;
#pragma unroll
            for (int jj = 0; jj < 4; ++jj) {
                int j = wv * 4 + jj;
                cp16(a_b + (size_t)jj * 8 * Fc + ko, db + j * 1024);
                cp16(b_b + (size_t)jj * 8 * Fc + ko, db + 16384 + j * 1024);
            }
        }

#pragma unroll
        for (int ks = 0; ks < 2; ++ks) {
            int cb0 = ks * 4 + quad;
            bf16x8 af[4];
#pragma unroll
            for (int mi = 0; mi < 4; ++mi) {
                int m = wm + mi * 16 + l16;
                af[mi] = *(const bf16x8*)(sb + m * 64 + ((cb0 ^ (m & 7)) * 8));
            }
#pragma unroll
            for (int ni = 0; ni < 4; ++ni) {
                int n = wn + ni * 16 + l16;
                bf16x8 bf = *(const bf16x8*)(sb + 8192 + n * 64 + ((cb0 ^ (n & 7)) * 8));
#pragma unroll
                for (int mi = 0; mi < 4; ++mi)
                    acc[mi][ni] = __builtin_amdgcn_mfma_f32_16x16x32_bf16(af[mi], bf, acc[mi][ni], 0, 0, 0);
            }
        }
        __syncthreads();
    }

#pragma unroll
    for (int mi = 0; mi < 4; ++mi)
#pragma unroll
        for (int r = 0; r < 4; ++r) {
            int m = wm + mi * 16 + quad * 4 + r;
            int grow = row0 + m;
            float wr = w_row[grow];
            if (wr != 0.f) {
                int t = tok_row[grow];
                float* op = out + (size_t)t * HDIM + n0;
#pragma unroll
                for (int ni = 0; ni < 4; ++ni)
                    atomicAdd(op + wn + ni * 16 + l16, wr * acc[mi][ni][r]);
            }
        }
}

extern "C" void kernel_launch(void* const* d_in, const int* in_sizes, int n_in,
                              void* d_out, int out_size, void* d_ws, size_t ws_size,
                              hipStream_t stream) {
    const float* x  = (const float*)d_in[0];
    const float* gw = (const float*)d_in[1];
    const float* w1 = (const float*)d_in[2];
    const float* w2 = (const float*)d_in[3];
    const float* w3 = (const float*)d_in[4];
    float* out = (float*)d_out;
    float* logits = out + (size_t)T * HDIM;

    char* ws = (char*)d_ws;
    size_t off = 0;
    auto alloc = [&](size_t b) {
        off = (off + 255) & ~(size_t)255;
        void* p = ws + off;
        off += b;
        return p;
    };
    int* cnt        = (int*)alloc(NE * 4);
    int* poff       = (int*)alloc((NE + 1) * 4);
    int* list       = (int*)alloc((size_t)NE * T * 4);
    float* wlist    = (float*)alloc((size_t)NE * T * 4);
    int* tok_row    = (int*)alloc(MAXROWS * 4);
    float* w_row    = (float*)alloc(MAXROWS * 4);
    unsigned short* xb = (unsigned short*)alloc((size_t)(T + 1) * HDIM * 2);  // +1 zero row
    size_t fixed_off = off;

    int Fc = 4096, fcShift = 12;
    for (;;) {
        size_t need = fixed_off + 3 * ((size_t)NE * Fc * HDIM * 2) + (size_t)MAXROWS * Fc * 2 + 1024;
        if (need <= ws_size || Fc == 512) break;
        Fc >>= 1; fcShift -= 1;
    }
    unsigned short* wb1 = (unsigned short*)alloc((size_t)NE * Fc * HDIM * 2);
    unsigned short* wb3 = (unsigned short*)alloc((size_t)NE * Fc * HDIM * 2);
    unsigned short* wb2 = (unsigned short*)alloc((size_t)NE * HDIM * Fc * 2);
    unsigned short* inter = (unsigned short*)alloc((size_t)MAXROWS * Fc * 2);

    hipMemsetAsync(cnt, 0, NE * 4, stream);
    hipMemsetAsync(out, 0, (size_t)T * HDIM * 4, stream);
    hipMemsetAsync(xb + (size_t)T * HDIM, 0, HDIM * 2, stream);
    conv_x_k<<<(T * HDIM / 8) / 256, 256, 0, stream>>>(x, xb);
    router_k<<<T / 64, 1024, 0, stream>>>(x, gw, logits, cnt, list, wlist);
    offsets_k<<<1, 64, 0, stream>>>(cnt, poff);
    compact_k<<<NE * T / 256, 256, 0, stream>>>(cnt, poff, list, wlist, tok_row, w_row);

    int nMT1 = MAXROWS / 256;  // 40 strips of 256 for gemm1
    int nMT2 = MAXROWS / 128;  // 80 strips of 128 for gemm2
    if (Fc == FDIM) {
        conv_all_k<<<dim3((size_t)NE * FDIM * HDIM / 8 / 256, 3), 256, 0, stream>>>(
            w1, w3, w2, wb1, wb3, wb2);
        gemm1_k<<<dim3(FDIM / 128, nMT1), 512, 0, stream>>>(xb, wb1, wb3, tok_row, poff, inter, FDIM);
        gemm2_k<<<dim3(HDIM / 128, nMT2), 256, 0, stream>>>(inter, wb2, tok_row, w_row, poff, out, FDIM);
    } else {
        for (int f0 = 0; f0 < FDIM; f0 += Fc) {
            conv_w13_k<<<dim3(Fc / 2, NE), 256, 0, stream>>>(w1, wb1, f0, Fc);
            conv_w13_k<<<dim3(Fc / 2, NE), 256, 0, stream>>>(w3, wb3, f0, Fc);
            conv_w2_k<<<dim3(HDIM * Fc / 2048, NE), 256, 0, stream>>>(w2, wb2, f0, Fc, fcShift);
            gemm1_k<<<dim3(Fc / 128, nMT1), 512, 0, stream>>>(xb, wb1, wb3, tok_row, poff, inter, Fc);
            gemm2_k<<<dim3(HDIM / 128, nMT2), 256, 0, stream>>>(inter, wb2, tok_row, w_row, poff, out, Fc);
        }
    }
}